// Round 9
// baseline (211.597 us; speedup 1.0000x reference)
//
#include <hip/hip_runtime.h>

#define B_   32
#define E_   512
#define HW_  256
#define S_   257
#define NH_  8
#define NBLK 1024
#define NTHR 256
#define NGRP 32
#define GSZ  32
#define LG_  260   // padded logit row stride

// smF layout (floats): [0..4111] phase scratch / w-tile; [4112..4143] RESERVED
// m-slice (persists across ALL phases); [4144..4399] zS; [4400..4415] scratch.
#define RES_M 4112
#define ZS_   4144
#define SCR_  4400
#define SMSZ  4416

__device__ __forceinline__ float wave_reduce(float v) {
  #pragma unroll
  for (int o = 32; o > 0; o >>= 1) v += __shfl_down(v, o, 64);
  return v;
}

// Group-local barrier (32 blocks of one batch), verified R3-R8. Block j
// write-through-stores its monotone phase number into word j of the group's
// 128-B slot line; wave 0 polls with system-scope relaxed loads (always served
// from the coherence point -> cannot spin stale). s_sleep(8) backoff.
__device__ __forceinline__ void gbar(unsigned* slots, int g, int j, int t, unsigned phase) {
  __syncthreads();                        // drains vmcnt: stores + atomics acked
  if (t < 64) {
    if (t == 0)
      __hip_atomic_store(&slots[g * GSZ + j], phase, __ATOMIC_RELAXED, __HIP_MEMORY_SCOPE_SYSTEM);
    const unsigned* line = slots + g * GSZ;
    int sl = t & 31;
    for (;;) {
      unsigned v = __hip_atomic_load(&line[sl], __ATOMIC_RELAXED, __HIP_MEMORY_SCOPE_SYSTEM);
      if (__all((int)(v >= phase))) break;
      __builtin_amdgcn_s_sleep(8);
    }
  }
  __syncthreads();
}

__global__ __launch_bounds__(NTHR, 4) void k_mega(
    const float* __restrict__ xr, const float* __restrict__ xi,
    const float* __restrict__ pos_r, const float* __restrict__ pos_i,
    const float* __restrict__ w_in_r, const float* __restrict__ w_in_i,
    const float* __restrict__ b_in_r, const float* __restrict__ b_in_i,
    const float* __restrict__ w_out_r, const float* __restrict__ w_out_i,
    const float* __restrict__ b_out_r, const float* __restrict__ b_out_i,
    const float* __restrict__ w_p_r, const float* __restrict__ w_p_i,
    const float* __restrict__ b_p_r, const float* __restrict__ b_p_i,
    unsigned* slots,
    float* __restrict__ q0a,
    float* __restrict__ l0r, float* __restrict__ l0i,
    float* __restrict__ lgr, float* __restrict__ lgi,
    float* __restrict__ a0r, float* __restrict__ a0i,
    float* __restrict__ out, int interleaved) {
  __shared__ __align__(16) float smF[SMSZ];
  const int t   = threadIdx.x;
  const int l   = t & 63;
  const int w   = t >> 6;
  const int bid = blockIdx.x;
  const int g   = bid >> 5;     // batch b (32 groups)
  const int j   = bid & 31;     // block within group
  const int e0  = 16 * j;       // this block's e-slice base (used by P1,P2,P3)
  float* mS = smF + RES_M;      // reserved m-slice [el*2 + ri], lives all phases

  // ---- P1: m-slice -> reserved LDS (never global), then partial q0[f] =
  //      sum_{e in slice} m[e]*w_q[f,e] for ALL 512 f, atomicAdd into q0a.
  //      (q0 is a sum over e; each block owns 16 e's -> m round-trip dies.) ----
  #pragma unroll
  for (int rr = 0; rr < 4; ++rr) {
    int el = w * 4 + rr;
    int e  = e0 + el;
    float4 vr = ((const float4*)(xr + ((size_t)g * E_ + e) * HW_))[l];
    float4 vi = ((const float4*)(xi + ((size_t)g * E_ + e) * HW_))[l];
    float sr = (vr.x + vr.y) + (vr.z + vr.w);
    float si = (vi.x + vi.y) + (vi.z + vi.w);
    sr = wave_reduce(sr); si = wave_reduce(si);
    if (l == 0) {
      mS[el * 2]     = sr * (1.f / HW_) + pos_r[(size_t)e * S_];
      mS[el * 2 + 1] = si * (1.f / HW_) + pos_i[(size_t)e * S_];
    }
  }
  __syncthreads();
  #pragma unroll
  for (int ff = 0; ff < 2; ++ff) {
    int f = t + ff * 256;
    const float* wr = w_in_r + (size_t)f * E_ + e0;
    const float* wi = w_in_i + (size_t)f * E_ + e0;
    float ar = 0.f, ai = 0.f;
    #pragma unroll
    for (int el = 0; el < 16; ++el) {
      float Xr = mS[el * 2], Xi = mS[el * 2 + 1];
      float Cr = wr[el], Ci = wi[el];
      ar += Xr * Cr - Xi * Ci;
      ai += Xr * Ci + Xi * Cr;
    }
    atomicAdd(&q0a[(size_t)g * 1024 + f * 2], ar);
    atomicAdd(&q0a[(size_t)g * 1024 + f * 2 + 1], ai);
  }
  gbar(slots, g, j, t, 1);

  // ---- P2: u[all h, own e-slice] computed block-locally (no u round-trip,
  //      no u barrier): u[h,el] = sum_d q0[h*64+d] * w_k[.,e0+el]; then
  //      logits + l0 partials (R7/R8-verified bodies), atomicAdd lgt/l0. ----
  {
    float* q0s = smF;            // 1024: [f*2 + ri], bias+scale applied
    float* us  = smF + 1024;     // 256:  [(el*8+h)*2 + ri]
    float* pu  = smF + 1280;     // 512:  [(dh*128 + el*8+h)*2 + ri]
    #pragma unroll
    for (int ff = 0; ff < 2; ++ff) {
      int f = t + ff * 256;
      q0s[f * 2]     = (q0a[(size_t)g * 1024 + f * 2]     + b_in_r[f]) * 0.125f;
      q0s[f * 2 + 1] = (q0a[(size_t)g * 1024 + f * 2 + 1] + b_in_i[f]) * 0.125f;
    }
    __syncthreads();
    {   // t -> (el = t&15, h = (t>>4)&7, d-half = t>>7)
      int el = t & 15, hh = (t >> 4) & 7, dh = t >> 7;
      float ar = 0.f, ai = 0.f;
      #pragma unroll 8
      for (int dd = 0; dd < 32; ++dd) {
        int f = hh * 64 + dh * 32 + dd;
        float qr = q0s[f * 2], qi = q0s[f * 2 + 1];
        float Wr = w_in_r[(size_t)(E_ + f) * E_ + e0 + el];
        float Wi = w_in_i[(size_t)(E_ + f) * E_ + e0 + el];
        ar += qr * Wr - qi * Wi;
        ai += qr * Wi + qi * Wr;
      }
      pu[(dh * 128 + el * 8 + hh) * 2]     = ar;
      pu[(dh * 128 + el * 8 + hh) * 2 + 1] = ai;
    }
    __syncthreads();
    if (t < 128) {
      int idx = t;   // el*8+h
      us[idx * 2]     = pu[idx * 2]     + pu[(128 + idx) * 2];
      us[idx * 2 + 1] = pu[idx * 2 + 1] + pu[(128 + idx) * 2 + 1];
    }
    __syncthreads();
    if (t < NH_) {                         // l0 chunk-partial for head t
      float pr = 0.f, pi = 0.f;
      #pragma unroll
      for (int el = 0; el < 16; ++el) {
        float Xr = mS[el * 2], Xi = mS[el * 2 + 1];
        float Ur = us[(el * 8 + t) * 2], Ui = us[(el * 8 + t) * 2 + 1];
        pr += Xr * Ur - Xi * Ui;
        pi += Xr * Ui + Xi * Ur;
      }
      atomicAdd(&l0r[g * NH_ + t], pr);
      atomicAdd(&l0i[g * NH_ + t], pi);
    }
    float ar[NH_], ai[NH_];
    #pragma unroll
    for (int hh = 0; hh < NH_; ++hh) { ar[hh] = 0.f; ai[hh] = 0.f; }
    const float* xrb = xr + ((size_t)g * E_ + e0) * HW_;
    const float* xib = xi + ((size_t)g * E_ + e0) * HW_;
    #pragma unroll 2
    for (int e = 0; e < 16; ++e) {
      float Xr = xrb[e * HW_ + t] + pos_r[(size_t)(e0 + e) * S_ + t + 1];
      float Xi = xib[e * HW_ + t] + pos_i[(size_t)(e0 + e) * S_ + t + 1];
      #pragma unroll
      for (int hh = 0; hh < NH_; ++hh) {
        float Ur = us[(e * 8 + hh) * 2], Ui = us[(e * 8 + hh) * 2 + 1];
        ar[hh] += Xr * Ur - Xi * Ui;
        ai[hh] += Xr * Ui + Xi * Ur;
      }
    }
    #pragma unroll
    for (int hh = 0; hh < NH_; ++hh) {
      size_t lb = (size_t)(g * NH_ + hh) * LG_ + t + 1;
      atomicAdd(&lgr[lb], ar[hh]);
      atomicAdd(&lgi[lb], ai[hh]);
    }
  }
  gbar(slots, g, j, t, 2);

  // ---- P3 (merged softmax + z + a0): every block loads all 8 logit rows into
  //      its w-tile, runs the 8 dual softmaxes itself (kills the softmax phase,
  //      its barrier, and the w2 round-trip), then the R8-verified z->a0 body. ----
  {
    float2* wls = (float2*)smF;                 // 2056 float2 = 16448 B
    float*  zS  = smF + ZS_;                    // [h][el]{r,i} = 256 floats
    float*  scr = smF + SCR_;                   // 16 floats
    for (int i = t; i < NH_ * S_; i += NTHR) {
      int hh = i / S_, k = i - hh * S_;
      float2 v;
      if (k == 0) { v.x = l0r[g * NH_ + hh];               v.y = l0i[g * NH_ + hh]; }
      else        { v.x = lgr[(size_t)(g * NH_ + hh) * LG_ + k];
                    v.y = lgi[(size_t)(g * NH_ + hh) * LG_ + k]; }
      wls[i] = v;
    }
    __syncthreads();
    // dual softmax per head, in place on wls (.x = real chain, .y = imag chain)
    for (int hh = 0; hh < NH_; ++hh) {
      float2 v    = wls[hh * S_ + t];
      float2 v256 = wls[hh * S_ + 256];
      float mr_ = v.x, mi_ = v.y;
      #pragma unroll
      for (int o = 32; o > 0; o >>= 1) {
        mr_ = fmaxf(mr_, __shfl_xor(mr_, o, 64));
        mi_ = fmaxf(mi_, __shfl_xor(mi_, o, 64));
      }
      if (l == 0) { scr[w * 2] = mr_; scr[w * 2 + 1] = mi_; }
      __syncthreads();
      float Mr = fmaxf(fmaxf(fmaxf(scr[0], scr[2]), fmaxf(scr[4], scr[6])), v256.x);
      float Mi = fmaxf(fmaxf(fmaxf(scr[1], scr[3]), fmaxf(scr[5], scr[7])), v256.y);
      float exr = expf(v.x - Mr), exi = expf(v.y - Mi);
      float e256r = expf(v256.x - Mr), e256i = expf(v256.y - Mi);
      float sr_ = exr, si_ = exi;
      #pragma unroll
      for (int o = 32; o > 0; o >>= 1) {
        sr_ += __shfl_xor(sr_, o, 64);
        si_ += __shfl_xor(si_, o, 64);
      }
      if (l == 0) { scr[8 + w * 2] = sr_; scr[9 + w * 2] = si_; }
      __syncthreads();
      float invr = 1.f / (scr[8] + scr[10] + scr[12] + scr[14] + e256r);
      float invi = 1.f / (scr[9] + scr[11] + scr[13] + scr[15] + e256i);
      float2 wv; wv.x = exr * invr; wv.y = exi * invi;
      wls[hh * S_ + t] = wv;
      if (t == 0) { float2 w2v; w2v.x = e256r * invr; w2v.y = e256i * invi; wls[hh * S_ + 256] = w2v; }
      __syncthreads();
    }
    // z for own e-slice -> LDS, then a0 partials (R8-verified body)
    #pragma unroll
    for (int rr = 0; rr < 4; ++rr) {
      int el = 4 * w + rr;
      int e  = e0 + el;                         // same x rows as P1/P2 -> warm
      const float* xre = xr + ((size_t)g * E_ + e) * HW_;
      const float* xie = xi + ((size_t)g * E_ + e) * HW_;
      const float* pre = pos_r + (size_t)e * S_;
      const float* pie = pos_i + (size_t)e * S_;
      float ar2[NH_], ai2[NH_];
      #pragma unroll
      for (int hh = 0; hh < NH_; ++hh) { ar2[hh] = 0.f; ai2[hh] = 0.f; }
      #pragma unroll
      for (int jj = 0; jj < 4; ++jj) {
        int k = 1 + l + 64 * jj;
        float Xr = xre[k - 1] + pre[k];
        float Xi = xie[k - 1] + pie[k];
        #pragma unroll
        for (int hh = 0; hh < NH_; ++hh) {
          float2 W = wls[hh * S_ + k];
          ar2[hh] += W.x * Xr - W.y * Xi;
          ai2[hh] += W.x * Xi + W.y * Xr;
        }
      }
      #pragma unroll
      for (int hh = 0; hh < NH_; ++hh) { ar2[hh] = wave_reduce(ar2[hh]); ai2[hh] = wave_reduce(ai2[hh]); }
      if (l == 0) {
        float X0r = mS[el * 2];
        float X0i = mS[el * 2 + 1];
        #pragma unroll
        for (int hh = 0; hh < NH_; ++hh) {
          float2 W0 = wls[hh * S_];
          zS[(hh * 16 + el) * 2]     = ar2[hh] + W0.x * X0r - W0.y * X0i;
          zS[(hh * 16 + el) * 2 + 1] = ai2[hh] + W0.x * X0i + W0.y * X0r;
        }
      }
    }
    __syncthreads();
    #pragma unroll
    for (int ff = 0; ff < 2; ++ff) {
      int f  = t + ff * 256;
      int hh = f >> 6;
      const float* wvr = w_in_r + (size_t)(2 * E_ + f) * E_ + e0;
      const float* wvi = w_in_i + (size_t)(2 * E_ + f) * E_ + e0;
      float cr = 0.f, ci = 0.f;
      #pragma unroll
      for (int el = 0; el < 16; ++el) {
        float Wr = wvr[el], Wi = wvi[el];
        float Zr = zS[(hh * 16 + el) * 2], Zi = zS[(hh * 16 + el) * 2 + 1];
        cr += Wr * Zr - Wi * Zi;
        ci += Wr * Zi + Wi * Zr;
      }
      if (j == 0) {                       // b_v*(1+i): sum of complex softmax = 1+i
        float bvr = b_in_r[2 * E_ + f], bvi = b_in_i[2 * E_ + f];
        cr += bvr - bvi;
        ci += bvr + bvi;
      }
      atomicAdd(&a0r[g * E_ + f], cr);
      atomicAdd(&a0i[g * E_ + f], ci);
    }
  }
  gbar(slots, g, j, t, 3);

  // ---- P4 (merged out-proj + final): ao for this block's 16 f' (incl. b_out),
  //      rank-16 contribution to out via atomicAdd (R8-verified). ----
  {
    float* aoS = smF;          // 32
    float* a0R = smF + 64;     // 512
    float* a0I = smF + 576;    // 512
    a0R[t]       = a0r[g * E_ + t];        a0I[t]       = a0i[g * E_ + t];
    a0R[t + 256] = a0r[g * E_ + t + 256];  a0I[t + 256] = a0i[g * E_ + t + 256];
    __syncthreads();
    #pragma unroll
    for (int rr = 0; rr < 4; ++rr) {
      int fl = w * 4 + rr;
      int f  = 16 * j + fl;
      const float* wrp = w_out_r + (size_t)f * E_;
      const float* wip = w_out_i + (size_t)f * E_;
      float ar = 0.f, ai = 0.f;
      #pragma unroll
      for (int e = l; e < E_; e += 64) {
        float Xr = a0R[e], Xi = a0I[e], Cr = wrp[e], Ci = wip[e];
        ar += Xr * Cr - Xi * Ci;
        ai += Xr * Ci + Xi * Cr;
      }
      ar = wave_reduce(ar); ai = wave_reduce(ai);
      if (l == 0) { aoS[fl * 2] = ar + b_out_r[f]; aoS[fl * 2 + 1] = ai + b_out_i[f]; }
    }
    __syncthreads();
    #pragma unroll
    for (int ff = 0; ff < 2; ++ff) {
      int o = t + ff * 256;
      const float* wpr = w_p_r + (size_t)o * E_ + 16 * j;
      const float* wpi = w_p_i + (size_t)o * E_ + 16 * j;
      float cr = 0.f, ci = 0.f;
      #pragma unroll
      for (int fl = 0; fl < 16; ++fl) {
        float Ar = aoS[fl * 2], Ai = aoS[fl * 2 + 1];
        float Wr = wpr[fl],     Wi = wpi[fl];
        cr += Ar * Wr - Ai * Wi;
        ci += Ar * Wi + Ai * Wr;
      }
      if (j == 0) { cr += b_p_r[o]; ci += b_p_i[o]; }
      int wid = g * E_ + o;
      if (interleaved) {
        atomicAdd(&out[(size_t)wid * 2],     cr);
        atomicAdd(&out[(size_t)wid * 2 + 1], ci);
      } else {
        atomicAdd(&out[wid], cr);
      }
    }
  }
}

extern "C" void kernel_launch(void* const* d_in, const int* in_sizes, int n_in,
                              void* d_out, int out_size, void* d_ws, size_t ws_size,
                              hipStream_t stream) {
  (void)in_sizes; (void)n_in; (void)ws_size;
  const float* xr      = (const float*)d_in[0];
  const float* xi      = (const float*)d_in[1];
  const float* pos_r   = (const float*)d_in[2];
  const float* pos_i   = (const float*)d_in[3];
  const float* w_in_r  = (const float*)d_in[4];
  const float* w_in_i  = (const float*)d_in[5];
  const float* b_in_r  = (const float*)d_in[6];
  const float* b_in_i  = (const float*)d_in[7];
  const float* w_out_r = (const float*)d_in[8];
  const float* w_out_i = (const float*)d_in[9];
  const float* b_out_r = (const float*)d_in[10];
  const float* b_out_i = (const float*)d_in[11];
  const float* w_p_r   = (const float*)d_in[12];
  const float* w_p_i   = (const float*)d_in[13];
  const float* b_p_r   = (const float*)d_in[14];
  const float* b_p_i   = (const float*)d_in[15];

  const int BE = B_ * E_;
  float* ws = (float*)d_ws;
  // ---- zeroed region (barrier slots + ALL atomic accumulators), contiguous ----
  unsigned* slots = (unsigned*)d_ws;             // 1024 u32 = 4 KB
  float* q0a  = ws + 1024;                       // 32 groups x 1024 = 32768
  float* l0r  = q0a + 32768;                     // 256
  float* l0i  = l0r + 256;                       // 256
  float* lgr  = l0i + 256;                       // B*NH*LG_ = 66560
  float* lgi  = lgr + B_ * NH_ * LG_;
  float* a0r  = lgi + B_ * NH_ * LG_;            // B*E = 16384
  float* a0i  = a0r + BE;

  int interleaved = out_size >= 2 * B_ * E_;

  // Zero slots + q0 + l0 + lgt + a0 accumulators (~0.8 MB) and the output
  // buffer (atomically accumulated). Dispatch-end writeback-invalidates also
  // clear stale L2 lines before k_mega starts.
  size_t zbytes = (size_t)(1024 + 32768 + 512 + 2 * B_ * NH_ * LG_ + 2 * BE) * 4;
  hipMemsetAsync(d_ws, 0, zbytes, stream);
  hipMemsetAsync(d_out, 0, (size_t)(interleaved ? 2 * BE : BE) * 4, stream);
  k_mega<<<NBLK, NTHR, 0, stream>>>(
      xr, xi, pos_r, pos_i, w_in_r, w_in_i, b_in_r, b_in_i,
      w_out_r, w_out_i, b_out_r, b_out_i, w_p_r, w_p_i, b_p_r, b_p_i,
      slots, q0a, l0r, l0i, lgr, lgi, a0r, a0i,
      (float*)d_out, interleaved);
}